// Round 18
// baseline (208.796 us; speedup 1.0000x reference)
//
#include <hip/hip_runtime.h>
#include <hip/hip_bf16.h>
#include <math.h>

// Multi-head self-attention w/ RoPE, causal. B=2, S=2048, H=16, hd=64, D=1024.
// fp32 inputs -> bf16 ws (+ RoPE cos/sin table for K) -> qkv GEMMs via
// global_load_lds (BK=32 linear LDS, 128x128 tiles; V as transposed GEMM ->
// coalesced V^T store) -> K-only table rope -> dual-chain flash attention
// (r10 pipelined schedule; r18: Q-rope fused into the Q-load prologue --
// in the A-operand fragment the feature axis is WITHIN the lane (8 consecutive
// d per frag = 4 complete RoPE pairs), so rotation is register-local with no
// shuffles, done once per block; theta = exp2(-0.415241*p) via raw v_exp) ->
// oproj 64x128 (r15: 2 blocks/CU).
// attn: dual 16-row chains/wave sharing K/V frags; QK(j+1) issued ahead of
// softmax(j); both chains' P-stores precede both P-reads; defer-max THR=11
// exp2-domain raw v_exp_f32; l via ones-MFMA; s_setprio; head-pinned XCD
// (n%8 = bx%8 -> FETCH 101->12.4MB, r3).
// History: r5/r12 rope fusions into GEMM C-fragments failed (feature axis
// across lanes -> shuffles/table scatter); Q-load fragments don't have that
// problem. K-rope stays a (half-sized) standalone pass: K frags reload ~16x
// per head, in-attn rotation would be 16x redundant VALU.
// ws: xb(8MB) wq/wk/wv/wo(2MB ea) q,k,vT(8MB ea) attn_out(8MB) = 48MB.
// RoPE table (512KB) at head of attn_out region: convert writes it, K-rope
// reads it, attn overwrites the region later (stream-ordered, race-free).

#define S_LEN 2048
#define NHEADS 16
#define HD 64
#define DM 1024

typedef __attribute__((ext_vector_type(8))) short bf16x8;  // MFMA A/B frag (4 VGPRs)
typedef __attribute__((ext_vector_type(4))) float f32x4;   // MFMA C/D frag

#define MFMA16(a, b, c) __builtin_amdgcn_mfma_f32_16x16x32_bf16((a), (b), (c), 0, 0, 0)
#define NEG_BIG (-1e30f)  // finite mask sentinel

#if __has_builtin(__builtin_amdgcn_exp2f)
#define EXP2F(x) __builtin_amdgcn_exp2f(x)   // raw v_exp_f32, 1 inst
#else
#define EXP2F(x) exp2f(x)
#endif

// async global->LDS, 16B per lane. LDS dest must be linear in lane order.
#define GLOAD_LDS16(g, l)                                                      \
    __builtin_amdgcn_global_load_lds(                                          \
        (const __attribute__((address_space(1))) void*)(g),                    \
        (__attribute__((address_space(3))) void*)(l), 16, 0, 0)

// ---------------------------------------------------------------------------
// fp32 -> bf16 conversion pre-pass + RoPE cos/sin table (plane y==8).
// ---------------------------------------------------------------------------
__global__ __launch_bounds__(256) void convert_kernel(
    const float* __restrict__ x,  const float* __restrict__ wq,
    const float* __restrict__ wk, const float* __restrict__ wv,
    const float* __restrict__ wo,
    __hip_bfloat16* __restrict__ xb,  __hip_bfloat16* __restrict__ wqb,
    __hip_bfloat16* __restrict__ wkb, __hip_bfloat16* __restrict__ wvb,
    __hip_bfloat16* __restrict__ wob, float2* __restrict__ tab)
{
    const int y = blockIdx.y;
    if (y == 8) {  // RoPE table: tab[s*32+p] = (cos, sin) of s*theta_p
        const int gid = blockIdx.x * 256 + threadIdx.x;
        if (gid < S_LEN * 32) {
            const int s = gid >> 5, p = gid & 31;
            float theta = powf(10000.0f, -(float)(2 * p) * (1.0f / 64.0f));
            float sn, cs;
            sincosf((float)s * theta, &sn, &cs);
            tab[gid] = make_float2(cs, sn);
        }
        return;
    }
    const float* src;
    __hip_bfloat16* dst;
    size_t off = 0;
    if (y < 4)      { src = x;  dst = xb;  off = (size_t)y * 1048576; }
    else if (y == 4) { src = wq; dst = wqb; }
    else if (y == 5) { src = wk; dst = wkb; }
    else if (y == 6) { src = wv; dst = wvb; }
    else             { src = wo; dst = wob; }

    const size_t i = off + ((size_t)blockIdx.x * 256 + threadIdx.x) * 4;
    float4 v = *(const float4*)(src + i);
    __hip_bfloat16 t[4] = { __float2bfloat16(v.x), __float2bfloat16(v.y),
                            __float2bfloat16(v.z), __float2bfloat16(v.w) };
    *(ushort4*)(dst + i) = *(ushort4*)t;
}

// ---------------------------------------------------------------------------
// GEMM, 128x128 tile, BK=32, 4 waves 2x2, global_load_lds staging.
// z=0,1 (Q,K): C[m=s_glob, n=feat] = X x W^T, out (B,H,S,hd) -- coalesced in d.
// z=2  (V^T):  C[m=feat, n=s_glob] = Wv x X^T, out (B,H,hd,S) -- coalesced in s.
// ---------------------------------------------------------------------------
__global__ __launch_bounds__(256) void qkv_kernel(
    const __hip_bfloat16* __restrict__ X,
    const __hip_bfloat16* __restrict__ Wq,
    const __hip_bfloat16* __restrict__ Wk,
    const __hip_bfloat16* __restrict__ Wv,
    __hip_bfloat16* __restrict__ qws,
    __hip_bfloat16* __restrict__ kws,
    __hip_bfloat16* __restrict__ vws)
{
    const int z = blockIdx.z;
    const bool vz = (z == 2);
    const __hip_bfloat16* __restrict__ Asrc = vz ? Wv : X;
    const __hip_bfloat16* __restrict__ Bsrc = vz ? X : ((z == 0) ? Wq : Wk);
    __hip_bfloat16* __restrict__ out = (z == 0) ? qws : (z == 1) ? kws : vws;

    __shared__ __align__(16) __hip_bfloat16 Asm[128 * 32];
    __shared__ __align__(16) __hip_bfloat16 Bsm[128 * 32];

    const int tid = threadIdx.x;
    const int wave = tid >> 6, lane = tid & 63;
    const int quad = lane >> 4, l15 = lane & 15;
    const int wm = (wave >> 1) * 64, wn = (wave & 1) * 64;
    const int m0 = vz ? blockIdx.x * 128 : blockIdx.y * 128;
    const int n0 = vz ? blockIdx.y * 128 : blockIdx.x * 128;

    f32x4 acc[4][4] = {};

    for (int k0 = 0; k0 < DM; k0 += 32) {
#pragma unroll
        for (int c = 0; c < 2; c++) {
            int idx = c * 2048 + tid * 8;           // element idx, 16B/lane
            int r = idx >> 5, kc = idx & 31;
            GLOAD_LDS16(Asrc + (size_t)(m0 + r) * DM + k0 + kc, &Asm[idx]);
            GLOAD_LDS16(Bsrc + (size_t)(n0 + r) * DM + k0 + kc, &Bsm[idx]);
        }
        __syncthreads();   // compiler emits vmcnt(0) drain before barrier
        bf16x8 af[4], bfv[4];
#pragma unroll
        for (int i = 0; i < 4; i++)
            af[i] = *(const bf16x8*)(&Asm[(wm + i * 16 + l15) * 32 + quad * 8]);
#pragma unroll
        for (int j = 0; j < 4; j++)
            bfv[j] = *(const bf16x8*)(&Bsm[(wn + j * 16 + l15) * 32 + quad * 8]);
#pragma unroll
        for (int i = 0; i < 4; i++)
#pragma unroll
            for (int j = 0; j < 4; j++)
                acc[i][j] = MFMA16(af[i], bfv[j], acc[i][j]);
        __syncthreads();
    }

#pragma unroll
    for (int i = 0; i < 4; i++) {
#pragma unroll
        for (int r = 0; r < 4; r++) {
            int m = m0 + wm + i * 16 + quad * 4 + r;
#pragma unroll
            for (int j = 0; j < 4; j++) {
                int col = n0 + wn + j * 16 + l15;
                size_t idx;
                if (vz) {
                    int h = m >> 6, d = m & 63;
                    int b = col >> 11, s = col & 2047;
                    idx = (((size_t)(b * NHEADS + h)) * HD + d) * S_LEN + s;  // V^T
                } else {
                    int b = m >> 11, s = m & 2047;
                    int h = col >> 6, d = col & 63;
                    idx = (((size_t)(b * NHEADS + h)) * S_LEN + s) * HD + d;  // Q,K
                }
                out[idx] = __float2bfloat16(acc[i][j][r]);
            }
        }
    }
}

// ---------------------------------------------------------------------------
// K-only RoPE in-place, (B,H,S,hd) layout, table-driven. (Q is rotated
// register-locally inside attn's Q-load prologue -- r18.)
// ---------------------------------------------------------------------------
__global__ __launch_bounds__(256) void rope_kernel(
    __hip_bfloat16* __restrict__ k, const float2* __restrict__ tab)
{
    const int gid = blockIdx.x * 256 + threadIdx.x;       // [0, 524288)
    const int e0 = gid * 8;
    const int s = (gid >> 3) & 2047;
    const int p4 = (gid & 7) * 4;                         // first pair index

    const float2* tp = tab + s * 32 + p4;                 // 4 float2, 32B aligned
    float4 t01 = *(const float4*)(tp);                    // cs0,sn0,cs1,sn1
    float4 t23 = *(const float4*)(tp + 2);                // cs2,sn2,cs3,sn3
    float cs[4] = { t01.x, t01.z, t23.x, t23.z };
    float sn[4] = { t01.y, t01.w, t23.y, t23.w };

    int4 raw = *(const int4*)(k + e0);
    __hip_bfloat16* v = (__hip_bfloat16*)&raw;
#pragma unroll
    for (int i = 0; i < 4; i++) {
        float x1 = __bfloat162float(v[2 * i]);
        float x2 = __bfloat162float(v[2 * i + 1]);
        v[2 * i]     = __float2bfloat16(x1 * cs[i] - x2 * sn[i]);
        v[2 * i + 1] = __float2bfloat16(x1 * sn[i] + x2 * cs[i]);
    }
    *(int4*)(k + e0) = raw;
}

// ---------------------------------------------------------------------------
// Dual-chain flash attention, pipelined schedule (r10, measured 71.7us),
// with fused register-local Q-rope (r18). Block = 4 independent waves; each
// wave runs TWO 16-row chains (rows q0+w*16 and +64 of a 128-row super-tile)
// sharing every K/V fragment load. Grid (32,16): bx = head -> n&7 = bx&7
// pins each head's blocks to one XCD (L2-resident K/V). qi = by<8 ? by :
// 23-by anti-pairs per CU.
// Q-rope: qf[st] holds 8 consecutive features d = st*32+quad*8..+7 = 4
// complete pairs IN-LANE; rotate once per block with theta_p =
// exp2(-log2(1e4)/32 * p) and fold in the 0.125*log2e softmax scale.
// Per-iteration schedule:
//   LOAD_VF(j) ; QK(j+1) both chains (kf = tile j+1) ; LOAD_KF(j+2) ;
//   SM_STORE(A,j) ; SM_STORE(B,j) ; PV_ACC(A) ; PV_ACC(B)
// Defer-max THR=11 (exp2 domain, ~e^8), raw v_exp_f32, l via ones-MFMA,
// wave-private LDS P transform, s_setprio around MFMA clusters.
// ---------------------------------------------------------------------------

#define QSCALE 0.18033688011112042f      // 0.125 * log2(e)
#define NL2TH  0.41524101186092029f      // log2(10000)/32

// register-local RoPE on a Q row fragment pair (once per block).
#define ROPEQ(qf, rowbase)                                                     \
    do {                                                                       \
        _Pragma("unroll")                                                      \
        for (int st = 0; st < 2; st++) {                                       \
            __hip_bfloat16* vv = (__hip_bfloat16*)&qf[st];                     \
            _Pragma("unroll")                                                  \
            for (int e = 0; e < 4; e++) {                                      \
                int p = st * 16 + quad * 4 + e;                                \
                float th = EXP2F(-NL2TH * (float)p);                           \
                float sn, cs;                                                  \
                sincosf((float)((rowbase) + l15) * th, &sn, &cs);              \
                float x1 = __bfloat162float(vv[2 * e]);                        \
                float x2 = __bfloat162float(vv[2 * e + 1]);                    \
                vv[2 * e]     = __float2bfloat16((x1 * cs - x2 * sn) * QSCALE);\
                vv[2 * e + 1] = __float2bfloat16((x1 * sn + x2 * cs) * QSCALE);\
            }                                                                  \
        }                                                                      \
    } while (0)

// softmax + P-store for one chain (no PV). Uses quad,l15,ones from scope.
#define SM_STORE(sc, mm, ll, oo, Pr)                                           \
    do {                                                                       \
        float pm[4];                                                           \
        _Pragma("unroll")                                                      \
        for (int r = 0; r < 4; r++)                                            \
            pm[r] = fmaxf(fmaxf(sc[0][r], sc[1][r]),                           \
                          fmaxf(sc[2][r], sc[3][r]));                          \
        bool ok = true;                                                        \
        _Pragma("unroll")                                                      \
        for (int r = 0; r < 4; r++) ok = ok && (pm[r] <= mm[r] + 11.0f);       \
        if (!__all(ok)) {                                                      \
            _Pragma("unroll")                                                  \
            for (int off = 1; off < 16; off <<= 1)                             \
                _Pragma("unroll")                                              \
                for (int r = 0; r < 4; r++)                                    \
                    pm[r] = fmaxf(pm[r], __shfl_xor(pm[r], off));              \
            _Pragma("unroll")                                                  \
            for (int r = 0; r < 4; r++) {                                      \
                float mn = fmaxf(mm[r], pm[r]);                                \
                float al = EXP2F(mm[r] - mn);                                  \
                mm[r] = mn;                                                    \
                ll[r] *= al;                                                   \
                _Pragma("unroll")                                              \
                for (int t = 0; t < 4; t++) oo[t][r] *= al;                    \
            }                                                                  \
        }                                                                      \
        _Pragma("unroll")                                                      \
        for (int t = 0; t < 4; t++)                                            \
            _Pragma("unroll")                                                  \
            for (int r = 0; r < 4; r++)                                        \
                Pr[(quad * 4 + r) * 72 + t * 16 + l15] =                       \
                    __float2bfloat16(EXP2F(sc[t][r] - mm[r]));                 \
    } while (0)

// P-read + l/O MFMA accumulation for one chain. Uses quad,l15,ones,vf.
#define PV_ACC(ll, oo, Pr)                                                     \
    do {                                                                       \
        _Pragma("unroll")                                                      \
        for (int st = 0; st < 2; st++) {                                       \
            bf16x8 pf = *(const bf16x8*)(&Pr[l15 * 72 + st * 32 + quad * 8]);  \
            __builtin_amdgcn_s_setprio(1);                                     \
            ll = MFMA16(pf, ones, ll);                                         \
            _Pragma("unroll")                                                  \
            for (int t = 0; t < 4; t++) oo[t] = MFMA16(pf, vf[st][t], oo[t]);  \
            __builtin_amdgcn_s_setprio(0);                                     \
        }                                                                      \
    } while (0)

#define LOAD_VF(kv0)                                                           \
    do {                                                                       \
        _Pragma("unroll")                                                      \
        for (int st = 0; st < 2; st++)                                         \
            _Pragma("unroll")                                                  \
            for (int t = 0; t < 4; t++)                                        \
                vf[st][t] = *(const bf16x8*)(Vtb +                             \
                    (size_t)(t * 16 + l15) * S_LEN + (kv0) + st * 32 + quad * 8); \
    } while (0)

#define LOAD_KF(kv0)                                                           \
    do {                                                                       \
        _Pragma("unroll")                                                      \
        for (int st = 0; st < 2; st++)                                         \
            _Pragma("unroll")                                                  \
            for (int t = 0; t < 4; t++)                                        \
                kf[st][t] = *(const bf16x8*)(Kb +                              \
                    (size_t)((kv0) + t * 16 + l15) * HD + st * 32 + quad * 8); \
    } while (0)

#define QK(sc, qf)                                                             \
    do {                                                                       \
        __builtin_amdgcn_s_setprio(1);                                         \
        _Pragma("unroll")                                                      \
        for (int st = 0; st < 2; st++)                                         \
            _Pragma("unroll")                                                  \
            for (int t = 0; t < 4; t++) sc[t] = MFMA16(qf[st], kf[st][t], sc[t]); \
        __builtin_amdgcn_s_setprio(0);                                         \
    } while (0)

#define MASK(sc, rowbase, kv0)                                                 \
    do {                                                                       \
        _Pragma("unroll")                                                      \
        for (int t = 0; t < 4; t++) {                                          \
            int col = (kv0) + t * 16 + l15;                                    \
            _Pragma("unroll")                                                  \
            for (int r = 0; r < 4; r++) {                                      \
                int row = (rowbase) + quad * 4 + r;                            \
                if (col > row) sc[t][r] = NEG_BIG;                             \
            }                                                                  \
        }                                                                      \
    } while (0)

__global__ __launch_bounds__(256) void attn_kernel(
    const __hip_bfloat16* __restrict__ Qg,
    const __hip_bfloat16* __restrict__ Kg,
    const __hip_bfloat16* __restrict__ Vtg,  // (B,H,hd,S)
    __hip_bfloat16* __restrict__ Og)         // (B,S,D)
{
    const int bh = blockIdx.x;                               // head -> XCD pin
    const int qi = (blockIdx.y < 8) ? blockIdx.y : 23 - blockIdx.y;
    const int tid = threadIdx.x;
    const int w = tid >> 6, lane = tid & 63;
    const int quad = lane >> 4, l15 = lane & 15;
    const size_t base = (size_t)bh * S_LEN * HD;
    const __hip_bfloat16* Qb = Qg + base;
    const __hip_bfloat16* Kb = Kg + base;
    const __hip_bfloat16* Vtb = Vtg + base;
    const int b = bh >> 4, h = bh & 15;

    __shared__ __align__(16) __hip_bfloat16 Pl[128 * 72];
    __hip_bfloat16* PrA = &Pl[w * 32 * 72];   // wave-private 16x64(+8 pad)
    __hip_bfloat16* PrB = PrA + 16 * 72;

    const int q0 = qi * 128;
    const int rowA = q0 + w * 16;             // chain A rows rowA..rowA+15
    const int rowB = rowA + 64;               // chain B rows

    bf16x8 qfA[2], qfB[2];
#pragma unroll
    for (int st = 0; st < 2; st++) {
        qfA[st] = *(const bf16x8*)(Qb + (size_t)(rowA + l15) * HD + st * 32 + quad * 8);
        qfB[st] = *(const bf16x8*)(Qb + (size_t)(rowB + l15) * HD + st * 32 + quad * 8);
    }
    ROPEQ(qfA, rowA);                         // register-local Q-rope + scale
    ROPEQ(qfB, rowB);

    bf16x8 ones;
#pragma unroll
    for (int i = 0; i < 8; i++) ones[i] = (short)0x3F80;  // bf16 1.0

    float mA[4], mB[4];
    f32x4 lA = {}, lB = {};
    f32x4 oA[4] = {}, oB[4] = {};
#pragma unroll
    for (int r = 0; r < 4; r++) { mA[r] = NEG_BIG; mB[r] = NEG_BIG; }

    bf16x8 kf[2][4];
    bf16x8 vf[2][4];

    // prologue: scores for tile 0; then kf <- tile 1
    LOAD_KF(0);
    f32x4 scA[4] = {}, scB[4] = {};
    QK(scA, qfA);
    QK(scB, qfB);
    LOAD_KF(64);

    // ---- full dual tiles: j = 0 .. 2qi-1 ----
    // invariant at loop top: scA/scB = scores(j), kf = K(j+1), V not loaded
#pragma unroll 1
    for (int j = 0; j < 2 * qi; j++) {
        const int kv0 = j * 64;
        LOAD_VF(kv0);
        f32x4 scAn[4] = {}, scBn[4] = {};
        QK(scAn, qfA);                        // scores(j+1), kf = tile j+1
        QK(scBn, qfB);
        LOAD_KF(kv0 + 128);                   // kf <- tile j+2 (<= 2qi+1 <= 31)
        SM_STORE(scA, mA, lA, oA, PrA);       // both stores before both reads
        SM_STORE(scB, mB, lB, oB, PrB);
        PV_ACC(lA, oA, PrA);
        PV_ACC(lB, oB, PrB);
#pragma unroll
        for (int t = 0; t < 4; t++) { scA[t] = scAn[t]; scB[t] = scBn[t]; }
    }

    // ---- tail: tile 2qi (A diag, B full); kf holds tile 2qi+1 ----
    {
        const int kv0 = q0;
        LOAD_VF(kv0);
        f32x4 scBn[4] = {};
        QK(scBn, qfB);                        // B scores for tile 2qi+1
        MASK(scA, rowA, kv0);
        SM_STORE(scA, mA, lA, oA, PrA);
        SM_STORE(scB, mB, lB, oB, PrB);
        PV_ACC(lA, oA, PrA);
        PV_ACC(lB, oB, PrB);

        // tile 2qi+1: B diagonal only
        const int kv1 = kv0 + 64;
        LOAD_VF(kv1);
        MASK(scBn, rowB, kv1);
        SM_STORE(scBn, mB, lB, oB, PrB);
        PV_ACC(lB, oB, PrB);
    }

    // epilogue: O/l -> (B,S,D), both chains
#pragma unroll
    for (int t = 0; t < 4; t++)
#pragma unroll
        for (int r = 0; r < 4; r++) {
            int d = t * 16 + l15;
            int sA = rowA + quad * 4 + r;
            Og[((size_t)(b * S_LEN + sA)) * DM + h * HD + d] =
                __float2bfloat16(oA[t][r] / lA[r]);
            int sB = rowB + quad * 4 + r;
            Og[((size_t)(b * S_LEN + sB)) * DM + h * HD + d] =
                __float2bfloat16(oB[t][r] / lB[r]);
        }
}

// ---------------------------------------------------------------------------
// Output projection: out = attn @ Wo^T -> d_out as fp32 (bf16-rounded).
// 64x128 tile (r15: 512 blocks = 2 blocks/CU vs 1 at 128x128). LDS 12KB.
// ---------------------------------------------------------------------------
__global__ __launch_bounds__(256) void oproj_kernel(
    const __hip_bfloat16* __restrict__ A,
    const __hip_bfloat16* __restrict__ W,
    float* __restrict__ out)
{
    __shared__ __align__(16) __hip_bfloat16 Asm[64 * 32];    // 4KB
    __shared__ __align__(16) __hip_bfloat16 Bsm[128 * 32];   // 8KB

    const int tid = threadIdx.x;
    const int wave = tid >> 6, lane = tid & 63;
    const int quad = lane >> 4, l15 = lane & 15;
    const int wm = (wave >> 1) * 32, wn = (wave & 1) * 64;
    const int m0 = blockIdx.y * 64, n0 = blockIdx.x * 128;

    f32x4 acc[2][4] = {};

    for (int k0 = 0; k0 < DM; k0 += 32) {
        {   // A: 64x32 = 2048 elems = 256 lanes x 8
            int idx = tid * 8;
            int r = idx >> 5, kc = idx & 31;
            GLOAD_LDS16(A + (size_t)(m0 + r) * DM + k0 + kc, &Asm[idx]);
        }
#pragma unroll
        for (int c = 0; c < 2; c++) {   // B: 128x32 = 4096 elems
            int idx = c * 2048 + tid * 8;
            int r = idx >> 5, kc = idx & 31;
            GLOAD_LDS16(W + (size_t)(n0 + r) * DM + k0 + kc, &Bsm[idx]);
        }
        __syncthreads();
        bf16x8 af[2], bfv[4];
#pragma unroll
        for (int i = 0; i < 2; i++)
            af[i] = *(const bf16x8*)(&Asm[(wm + i * 16 + l15) * 32 + quad * 8]);
#pragma unroll
        for (int j = 0; j < 4; j++)
            bfv[j] = *(const bf16x8*)(&Bsm[(wn + j * 16 + l15) * 32 + quad * 8]);
#pragma unroll
        for (int i = 0; i < 2; i++)
#pragma unroll
            for (int j = 0; j < 4; j++)
                acc[i][j] = MFMA16(af[i], bfv[j], acc[i][j]);
        __syncthreads();
    }

#pragma unroll
    for (int i = 0; i < 2; i++)
#pragma unroll
        for (int r = 0; r < 4; r++) {
            int m = m0 + wm + i * 16 + quad * 4 + r;
#pragma unroll
            for (int j = 0; j < 4; j++) {
                int col = n0 + wn + j * 16 + l15;
                __hip_bfloat16 bb = __float2bfloat16(acc[i][j][r]);
                unsigned int u = ((unsigned int)(*(unsigned short*)&bb)) << 16;
                out[(size_t)m * DM + col] = __uint_as_float(u);
            }
        }
}

// ---------------------------------------------------------------------------
extern "C" void kernel_launch(void* const* d_in, const int* in_sizes, int n_in,
                              void* d_out, int out_size, void* d_ws, size_t ws_size,
                              hipStream_t stream)
{
    const float* x  = (const float*)d_in[0];
    const float* wq = (const float*)d_in[1];
    const float* wk = (const float*)d_in[2];
    const float* wv = (const float*)d_in[3];
    const float* wo = (const float*)d_in[4];
    float* out = (float*)d_out;

    const size_t xe = (size_t)2 * S_LEN * DM;
    const size_t we = (size_t)DM * DM;
    __hip_bfloat16* xb  = (__hip_bfloat16*)d_ws;
    __hip_bfloat16* wqb = xb + xe;
    __hip_bfloat16* wkb = wqb + we;
    __hip_bfloat16* wvb = wkb + we;
    __hip_bfloat16* wob = wvb + we;
    __hip_bfloat16* qws = wob + we;
    __hip_bfloat16* kws = qws + xe;
    __hip_bfloat16* vws = kws + xe;   // V^T (B,H,hd,S)
    __hip_bfloat16* aws = vws + xe;
    float2* tab = (float2*)aws;       // RoPE table: reuses attn_out region,
                                      // consumed (K-rope) before aws is written

    dim3 blk(256, 1, 1);
    convert_kernel<<<dim3(1024, 9, 1), blk, 0, stream>>>(x, wq, wk, wv, wo,
                                                         xb, wqb, wkb, wvb, wob, tab);
    qkv_kernel<<<dim3(8, 32, 3), blk, 0, stream>>>(xb, wqb, wkb, wvb, qws, kws, vws);
    rope_kernel<<<dim3(2048, 1, 1), blk, 0, stream>>>(kws, tab);
    attn_kernel<<<dim3(32, 16, 1), blk, 0, stream>>>(qws, kws, vws, aws);
    oproj_kernel<<<dim3(8, 64, 1), blk, 0, stream>>>(aws, wob, out);
}

// Round 19
// 206.427 us; speedup vs baseline: 1.0115x; 1.0115x over previous
//
#include <hip/hip_runtime.h>
#include <hip/hip_bf16.h>
#include <math.h>

// Multi-head self-attention w/ RoPE, causal. B=2, S=2048, H=16, hd=64, D=1024.
// fp32 inputs -> bf16 ws (+ RoPE cos/sin table for K) -> qkv GEMMs via
// global_load_lds (BK=32 linear LDS, 128x128 tiles; V as transposed GEMM ->
// coalesced V^T store) -> K-only table rope -> dual-chain flash attention
// (r10 pipelined schedule; Q-rope fused into the Q-load prologue,
// register-local). -> oproj 64x128 (r15: 2 blocks/CU).
// r19 fix of r18: ROPEQ used sincosf in RADIANS with args up to ~2047 ->
// OCML Payne-Hanek slow path (~1k cyc/call x32) -> attn 72->104us,
// MfmaUtil 10.4->7.4. Replaced with hardware v_sin/v_cos (REVOLUTIONS:
// sin(x) = v_sin(fract(x/2pi)), ~5 VALU/pair, no libm, no table -> no race
// with attn's aws writes). Angle error <=1.2e-4 rad << bf16 rounding.
// attn: dual 16-row chains/wave sharing K/V frags; QK(j+1) issued ahead of
// softmax(j); both chains' P-stores precede both P-reads; defer-max THR=11
// exp2-domain raw v_exp_f32; l via ones-MFMA; s_setprio; head-pinned XCD
// (n%8 = bx%8 -> FETCH 101->12.4MB, r3).
// ws: xb(8MB) wq/wk/wv/wo(2MB ea) q,k,vT(8MB ea) attn_out(8MB) = 48MB.
// RoPE table (512KB) at head of attn_out region: convert writes it, K-rope
// reads it, attn overwrites the region later (stream-ordered, race-free).

#define S_LEN 2048
#define NHEADS 16
#define HD 64
#define DM 1024

typedef __attribute__((ext_vector_type(8))) short bf16x8;  // MFMA A/B frag (4 VGPRs)
typedef __attribute__((ext_vector_type(4))) float f32x4;   // MFMA C/D frag

#define MFMA16(a, b, c) __builtin_amdgcn_mfma_f32_16x16x32_bf16((a), (b), (c), 0, 0, 0)
#define NEG_BIG (-1e30f)  // finite mask sentinel

#if __has_builtin(__builtin_amdgcn_exp2f)
#define EXP2F(x) __builtin_amdgcn_exp2f(x)   // raw v_exp_f32, 1 inst
#else
#define EXP2F(x) exp2f(x)
#endif

// hardware sin/cos in REVOLUTIONS (v_sin_f32/v_cos_f32): sin(2*pi*x).
#if __has_builtin(__builtin_amdgcn_sinf)
#define HSIN(rev) __builtin_amdgcn_sinf(rev)
#define HCOS(rev) __builtin_amdgcn_cosf(rev)
#else
#define HSIN(rev) sinf((rev) * 6.2831853071795864f)
#define HCOS(rev) cosf((rev) * 6.2831853071795864f)
#endif
#define INV2PI 0.15915494309189535f

// async global->LDS, 16B per lane. LDS dest must be linear in lane order.
#define GLOAD_LDS16(g, l)                                                      \
    __builtin_amdgcn_global_load_lds(                                          \
        (const __attribute__((address_space(1))) void*)(g),                    \
        (__attribute__((address_space(3))) void*)(l), 16, 0, 0)

// ---------------------------------------------------------------------------
// fp32 -> bf16 conversion pre-pass + RoPE cos/sin table (plane y==8).
// ---------------------------------------------------------------------------
__global__ __launch_bounds__(256) void convert_kernel(
    const float* __restrict__ x,  const float* __restrict__ wq,
    const float* __restrict__ wk, const float* __restrict__ wv,
    const float* __restrict__ wo,
    __hip_bfloat16* __restrict__ xb,  __hip_bfloat16* __restrict__ wqb,
    __hip_bfloat16* __restrict__ wkb, __hip_bfloat16* __restrict__ wvb,
    __hip_bfloat16* __restrict__ wob, float2* __restrict__ tab)
{
    const int y = blockIdx.y;
    if (y == 8) {  // RoPE table: tab[s*32+p] = (cos, sin) of s*theta_p
        const int gid = blockIdx.x * 256 + threadIdx.x;
        if (gid < S_LEN * 32) {
            const int s = gid >> 5, p = gid & 31;
            float theta = powf(10000.0f, -(float)(2 * p) * (1.0f / 64.0f));
            float sn, cs;
            sincosf((float)s * theta, &sn, &cs);
            tab[gid] = make_float2(cs, sn);
        }
        return;
    }
    const float* src;
    __hip_bfloat16* dst;
    size_t off = 0;
    if (y < 4)      { src = x;  dst = xb;  off = (size_t)y * 1048576; }
    else if (y == 4) { src = wq; dst = wqb; }
    else if (y == 5) { src = wk; dst = wkb; }
    else if (y == 6) { src = wv; dst = wvb; }
    else             { src = wo; dst = wob; }

    const size_t i = off + ((size_t)blockIdx.x * 256 + threadIdx.x) * 4;
    float4 v = *(const float4*)(src + i);
    __hip_bfloat16 t[4] = { __float2bfloat16(v.x), __float2bfloat16(v.y),
                            __float2bfloat16(v.z), __float2bfloat16(v.w) };
    *(ushort4*)(dst + i) = *(ushort4*)t;
}

// ---------------------------------------------------------------------------
// GEMM, 128x128 tile, BK=32, 4 waves 2x2, global_load_lds staging.
// z=0,1 (Q,K): C[m=s_glob, n=feat] = X x W^T, out (B,H,S,hd) -- coalesced in d.
// z=2  (V^T):  C[m=feat, n=s_glob] = Wv x X^T, out (B,H,hd,S) -- coalesced in s.
// ---------------------------------------------------------------------------
__global__ __launch_bounds__(256) void qkv_kernel(
    const __hip_bfloat16* __restrict__ X,
    const __hip_bfloat16* __restrict__ Wq,
    const __hip_bfloat16* __restrict__ Wk,
    const __hip_bfloat16* __restrict__ Wv,
    __hip_bfloat16* __restrict__ qws,
    __hip_bfloat16* __restrict__ kws,
    __hip_bfloat16* __restrict__ vws)
{
    const int z = blockIdx.z;
    const bool vz = (z == 2);
    const __hip_bfloat16* __restrict__ Asrc = vz ? Wv : X;
    const __hip_bfloat16* __restrict__ Bsrc = vz ? X : ((z == 0) ? Wq : Wk);
    __hip_bfloat16* __restrict__ out = (z == 0) ? qws : (z == 1) ? kws : vws;

    __shared__ __align__(16) __hip_bfloat16 Asm[128 * 32];
    __shared__ __align__(16) __hip_bfloat16 Bsm[128 * 32];

    const int tid = threadIdx.x;
    const int wave = tid >> 6, lane = tid & 63;
    const int quad = lane >> 4, l15 = lane & 15;
    const int wm = (wave >> 1) * 64, wn = (wave & 1) * 64;
    const int m0 = vz ? blockIdx.x * 128 : blockIdx.y * 128;
    const int n0 = vz ? blockIdx.y * 128 : blockIdx.x * 128;

    f32x4 acc[4][4] = {};

    for (int k0 = 0; k0 < DM; k0 += 32) {
#pragma unroll
        for (int c = 0; c < 2; c++) {
            int idx = c * 2048 + tid * 8;           // element idx, 16B/lane
            int r = idx >> 5, kc = idx & 31;
            GLOAD_LDS16(Asrc + (size_t)(m0 + r) * DM + k0 + kc, &Asm[idx]);
            GLOAD_LDS16(Bsrc + (size_t)(n0 + r) * DM + k0 + kc, &Bsm[idx]);
        }
        __syncthreads();   // compiler emits vmcnt(0) drain before barrier
        bf16x8 af[4], bfv[4];
#pragma unroll
        for (int i = 0; i < 4; i++)
            af[i] = *(const bf16x8*)(&Asm[(wm + i * 16 + l15) * 32 + quad * 8]);
#pragma unroll
        for (int j = 0; j < 4; j++)
            bfv[j] = *(const bf16x8*)(&Bsm[(wn + j * 16 + l15) * 32 + quad * 8]);
#pragma unroll
        for (int i = 0; i < 4; i++)
#pragma unroll
            for (int j = 0; j < 4; j++)
                acc[i][j] = MFMA16(af[i], bfv[j], acc[i][j]);
        __syncthreads();
    }

#pragma unroll
    for (int i = 0; i < 4; i++) {
#pragma unroll
        for (int r = 0; r < 4; r++) {
            int m = m0 + wm + i * 16 + quad * 4 + r;
#pragma unroll
            for (int j = 0; j < 4; j++) {
                int col = n0 + wn + j * 16 + l15;
                size_t idx;
                if (vz) {
                    int h = m >> 6, d = m & 63;
                    int b = col >> 11, s = col & 2047;
                    idx = (((size_t)(b * NHEADS + h)) * HD + d) * S_LEN + s;  // V^T
                } else {
                    int b = m >> 11, s = m & 2047;
                    int h = col >> 6, d = col & 63;
                    idx = (((size_t)(b * NHEADS + h)) * S_LEN + s) * HD + d;  // Q,K
                }
                out[idx] = __float2bfloat16(acc[i][j][r]);
            }
        }
    }
}

// ---------------------------------------------------------------------------
// K-only RoPE in-place, (B,H,S,hd) layout, table-driven. (Q is rotated
// register-locally inside attn's Q-load prologue.)
// ---------------------------------------------------------------------------
__global__ __launch_bounds__(256) void rope_kernel(
    __hip_bfloat16* __restrict__ k, const float2* __restrict__ tab)
{
    const int gid = blockIdx.x * 256 + threadIdx.x;       // [0, 524288)
    const int e0 = gid * 8;
    const int s = (gid >> 3) & 2047;
    const int p4 = (gid & 7) * 4;                         // first pair index

    const float2* tp = tab + s * 32 + p4;                 // 4 float2, 32B aligned
    float4 t01 = *(const float4*)(tp);                    // cs0,sn0,cs1,sn1
    float4 t23 = *(const float4*)(tp + 2);                // cs2,sn2,cs3,sn3
    float cs[4] = { t01.x, t01.z, t23.x, t23.z };
    float sn[4] = { t01.y, t01.w, t23.y, t23.w };

    int4 raw = *(const int4*)(k + e0);
    __hip_bfloat16* v = (__hip_bfloat16*)&raw;
#pragma unroll
    for (int i = 0; i < 4; i++) {
        float x1 = __bfloat162float(v[2 * i]);
        float x2 = __bfloat162float(v[2 * i + 1]);
        v[2 * i]     = __float2bfloat16(x1 * cs[i] - x2 * sn[i]);
        v[2 * i + 1] = __float2bfloat16(x1 * sn[i] + x2 * cs[i]);
    }
    *(int4*)(k + e0) = raw;
}

// ---------------------------------------------------------------------------
// Dual-chain flash attention, pipelined schedule (r10, measured 71.7us),
// with fused register-local Q-rope via HW v_sin/v_cos (r19). Block = 4
// independent waves; each wave runs TWO 16-row chains (rows q0+w*16 and +64
// of a 128-row super-tile) sharing every K/V fragment load. Grid (32,16):
// bx = head -> n&7 = bx&7 pins each head's blocks to one XCD. qi = by<8 ?
// by : 23-by anti-pairs per CU.
// Q-rope: qf[st] holds 8 consecutive features = 4 complete pairs IN-LANE;
// rotate once per block: theta_p = exp2(-log2(1e4)/32*p), angle in
// REVOLUTIONS = s*theta*INV2PI, fract, v_sin/v_cos; fold in 0.125*log2e.
// Per-iteration schedule:
//   LOAD_VF(j) ; QK(j+1) both chains (kf = tile j+1) ; LOAD_KF(j+2) ;
//   SM_STORE(A,j) ; SM_STORE(B,j) ; PV_ACC(A) ; PV_ACC(B)
// Defer-max THR=11 (exp2 domain, ~e^8), raw v_exp_f32, l via ones-MFMA,
// wave-private LDS P transform, s_setprio around MFMA clusters.
// ---------------------------------------------------------------------------

#define QSCALE 0.18033688011112042f      // 0.125 * log2(e)
#define NL2TH  0.41524101186092029f      // log2(10000)/32

// register-local RoPE on a Q row fragment pair (once per block), HW trig.
#define ROPEQ(qf, rowbase)                                                     \
    do {                                                                       \
        _Pragma("unroll")                                                      \
        for (int st = 0; st < 2; st++) {                                       \
            __hip_bfloat16* vv = (__hip_bfloat16*)&qf[st];                     \
            _Pragma("unroll")                                                  \
            for (int e = 0; e < 4; e++) {                                      \
                int p = st * 16 + quad * 4 + e;                                \
                float th = EXP2F(-NL2TH * (float)p);                           \
                float rev = (float)((rowbase) + l15) * th * INV2PI;            \
                rev -= floorf(rev);                                            \
                float sn = HSIN(rev), cs = HCOS(rev);                          \
                float x1 = __bfloat162float(vv[2 * e]);                        \
                float x2 = __bfloat162float(vv[2 * e + 1]);                    \
                vv[2 * e]     = __float2bfloat16((x1 * cs - x2 * sn) * QSCALE);\
                vv[2 * e + 1] = __float2bfloat16((x1 * sn + x2 * cs) * QSCALE);\
            }                                                                  \
        }                                                                      \
    } while (0)

// softmax + P-store for one chain (no PV). Uses quad,l15,ones from scope.
#define SM_STORE(sc, mm, ll, oo, Pr)                                           \
    do {                                                                       \
        float pm[4];                                                           \
        _Pragma("unroll")                                                      \
        for (int r = 0; r < 4; r++)                                            \
            pm[r] = fmaxf(fmaxf(sc[0][r], sc[1][r]),                           \
                          fmaxf(sc[2][r], sc[3][r]));                          \
        bool ok = true;                                                        \
        _Pragma("unroll")                                                      \
        for (int r = 0; r < 4; r++) ok = ok && (pm[r] <= mm[r] + 11.0f);       \
        if (!__all(ok)) {                                                      \
            _Pragma("unroll")                                                  \
            for (int off = 1; off < 16; off <<= 1)                             \
                _Pragma("unroll")                                              \
                for (int r = 0; r < 4; r++)                                    \
                    pm[r] = fmaxf(pm[r], __shfl_xor(pm[r], off));              \
            _Pragma("unroll")                                                  \
            for (int r = 0; r < 4; r++) {                                      \
                float mn = fmaxf(mm[r], pm[r]);                                \
                float al = EXP2F(mm[r] - mn);                                  \
                mm[r] = mn;                                                    \
                ll[r] *= al;                                                   \
                _Pragma("unroll")                                              \
                for (int t = 0; t < 4; t++) oo[t][r] *= al;                    \
            }                                                                  \
        }                                                                      \
        _Pragma("unroll")                                                      \
        for (int t = 0; t < 4; t++)                                            \
            _Pragma("unroll")                                                  \
            for (int r = 0; r < 4; r++)                                        \
                Pr[(quad * 4 + r) * 72 + t * 16 + l15] =                       \
                    __float2bfloat16(EXP2F(sc[t][r] - mm[r]));                 \
    } while (0)

// P-read + l/O MFMA accumulation for one chain. Uses quad,l15,ones,vf.
#define PV_ACC(ll, oo, Pr)                                                     \
    do {                                                                       \
        _Pragma("unroll")                                                      \
        for (int st = 0; st < 2; st++) {                                       \
            bf16x8 pf = *(const bf16x8*)(&Pr[l15 * 72 + st * 32 + quad * 8]);  \
            __builtin_amdgcn_s_setprio(1);                                     \
            ll = MFMA16(pf, ones, ll);                                         \
            _Pragma("unroll")                                                  \
            for (int t = 0; t < 4; t++) oo[t] = MFMA16(pf, vf[st][t], oo[t]);  \
            __builtin_amdgcn_s_setprio(0);                                     \
        }                                                                      \
    } while (0)

#define LOAD_VF(kv0)                                                           \
    do {                                                                       \
        _Pragma("unroll")                                                      \
        for (int st = 0; st < 2; st++)                                         \
            _Pragma("unroll")                                                  \
            for (int t = 0; t < 4; t++)                                        \
                vf[st][t] = *(const bf16x8*)(Vtb +                             \
                    (size_t)(t * 16 + l15) * S_LEN + (kv0) + st * 32 + quad * 8); \
    } while (0)

#define LOAD_KF(kv0)                                                           \
    do {                                                                       \
        _Pragma("unroll")                                                      \
        for (int st = 0; st < 2; st++)                                         \
            _Pragma("unroll")                                                  \
            for (int t = 0; t < 4; t++)                                        \
                kf[st][t] = *(const bf16x8*)(Kb +                              \
                    (size_t)((kv0) + t * 16 + l15) * HD + st * 32 + quad * 8); \
    } while (0)

#define QK(sc, qf)                                                             \
    do {                                                                       \
        __builtin_amdgcn_s_setprio(1);                                         \
        _Pragma("unroll")                                                      \
        for (int st = 0; st < 2; st++)                                         \
            _Pragma("unroll")                                                  \
            for (int t = 0; t < 4; t++) sc[t] = MFMA16(qf[st], kf[st][t], sc[t]); \
        __builtin_amdgcn_s_setprio(0);                                         \
    } while (0)

#define MASK(sc, rowbase, kv0)                                                 \
    do {                                                                       \
        _Pragma("unroll")                                                      \
        for (int t = 0; t < 4; t++) {                                          \
            int col = (kv0) + t * 16 + l15;                                    \
            _Pragma("unroll")                                                  \
            for (int r = 0; r < 4; r++) {                                      \
                int row = (rowbase) + quad * 4 + r;                            \
                if (col > row) sc[t][r] = NEG_BIG;                             \
            }                                                                  \
        }                                                                      \
    } while (0)

__global__ __launch_bounds__(256) void attn_kernel(
    const __hip_bfloat16* __restrict__ Qg,
    const __hip_bfloat16* __restrict__ Kg,
    const __hip_bfloat16* __restrict__ Vtg,  // (B,H,hd,S)
    __hip_bfloat16* __restrict__ Og)         // (B,S,D)
{
    const int bh = blockIdx.x;                               // head -> XCD pin
    const int qi = (blockIdx.y < 8) ? blockIdx.y : 23 - blockIdx.y;
    const int tid = threadIdx.x;
    const int w = tid >> 6, lane = tid & 63;
    const int quad = lane >> 4, l15 = lane & 15;
    const size_t base = (size_t)bh * S_LEN * HD;
    const __hip_bfloat16* Qb = Qg + base;
    const __hip_bfloat16* Kb = Kg + base;
    const __hip_bfloat16* Vtb = Vtg + base;
    const int b = bh >> 4, h = bh & 15;

    __shared__ __align__(16) __hip_bfloat16 Pl[128 * 72];
    __hip_bfloat16* PrA = &Pl[w * 32 * 72];   // wave-private 16x64(+8 pad)
    __hip_bfloat16* PrB = PrA + 16 * 72;

    const int q0 = qi * 128;
    const int rowA = q0 + w * 16;             // chain A rows rowA..rowA+15
    const int rowB = rowA + 64;               // chain B rows

    bf16x8 qfA[2], qfB[2];
#pragma unroll
    for (int st = 0; st < 2; st++) {
        qfA[st] = *(const bf16x8*)(Qb + (size_t)(rowA + l15) * HD + st * 32 + quad * 8);
        qfB[st] = *(const bf16x8*)(Qb + (size_t)(rowB + l15) * HD + st * 32 + quad * 8);
    }
    ROPEQ(qfA, rowA);                         // register-local Q-rope + scale
    ROPEQ(qfB, rowB);

    bf16x8 ones;
#pragma unroll
    for (int i = 0; i < 8; i++) ones[i] = (short)0x3F80;  // bf16 1.0

    float mA[4], mB[4];
    f32x4 lA = {}, lB = {};
    f32x4 oA[4] = {}, oB[4] = {};
#pragma unroll
    for (int r = 0; r < 4; r++) { mA[r] = NEG_BIG; mB[r] = NEG_BIG; }

    bf16x8 kf[2][4];
    bf16x8 vf[2][4];

    // prologue: scores for tile 0; then kf <- tile 1
    LOAD_KF(0);
    f32x4 scA[4] = {}, scB[4] = {};
    QK(scA, qfA);
    QK(scB, qfB);
    LOAD_KF(64);

    // ---- full dual tiles: j = 0 .. 2qi-1 ----
    // invariant at loop top: scA/scB = scores(j), kf = K(j+1), V not loaded
#pragma unroll 1
    for (int j = 0; j < 2 * qi; j++) {
        const int kv0 = j * 64;
        LOAD_VF(kv0);
        f32x4 scAn[4] = {}, scBn[4] = {};
        QK(scAn, qfA);                        // scores(j+1), kf = tile j+1
        QK(scBn, qfB);
        LOAD_KF(kv0 + 128);                   // kf <- tile j+2 (<= 2qi+1 <= 31)
        SM_STORE(scA, mA, lA, oA, PrA);       // both stores before both reads
        SM_STORE(scB, mB, lB, oB, PrB);
        PV_ACC(lA, oA, PrA);
        PV_ACC(lB, oB, PrB);
#pragma unroll
        for (int t = 0; t < 4; t++) { scA[t] = scAn[t]; scB[t] = scBn[t]; }
    }

    // ---- tail: tile 2qi (A diag, B full); kf holds tile 2qi+1 ----
    {
        const int kv0 = q0;
        LOAD_VF(kv0);
        f32x4 scBn[4] = {};
        QK(scBn, qfB);                        // B scores for tile 2qi+1
        MASK(scA, rowA, kv0);
        SM_STORE(scA, mA, lA, oA, PrA);
        SM_STORE(scB, mB, lB, oB, PrB);
        PV_ACC(lA, oA, PrA);
        PV_ACC(lB, oB, PrB);

        // tile 2qi+1: B diagonal only
        const int kv1 = kv0 + 64;
        LOAD_VF(kv1);
        MASK(scBn, rowB, kv1);
        SM_STORE(scBn, mB, lB, oB, PrB);
        PV_ACC(lB, oB, PrB);
    }

    // epilogue: O/l -> (B,S,D), both chains
#pragma unroll
    for (int t = 0; t < 4; t++)
#pragma unroll
        for (int r = 0; r < 4; r++) {
            int d = t * 16 + l15;
            int sA = rowA + quad * 4 + r;
            Og[((size_t)(b * S_LEN + sA)) * DM + h * HD + d] =
                __float2bfloat16(oA[t][r] / lA[r]);
            int sB = rowB + quad * 4 + r;
            Og[((size_t)(b * S_LEN + sB)) * DM + h * HD + d] =
                __float2bfloat16(oB[t][r] / lB[r]);
        }
}

// ---------------------------------------------------------------------------
// Output projection: out = attn @ Wo^T -> d_out as fp32 (bf16-rounded).
// 64x128 tile (r15: 512 blocks = 2 blocks/CU vs 1 at 128x128). LDS 12KB.
// ---------------------------------------------------------------------------
__global__ __launch_bounds__(256) void oproj_kernel(
    const __hip_bfloat16* __restrict__ A,
    const __hip_bfloat16* __restrict__ W,
    float* __restrict__ out)
{
    __shared__ __align__(16) __hip_bfloat16 Asm[64 * 32];    // 4KB
    __shared__ __align__(16) __hip_bfloat16 Bsm[128 * 32];   // 8KB

    const int tid = threadIdx.x;
    const int wave = tid >> 6, lane = tid & 63;
    const int quad = lane >> 4, l15 = lane & 15;
    const int wm = (wave >> 1) * 32, wn = (wave & 1) * 64;
    const int m0 = blockIdx.y * 64, n0 = blockIdx.x * 128;

    f32x4 acc[2][4] = {};

    for (int k0 = 0; k0 < DM; k0 += 32) {
        {   // A: 64x32 = 2048 elems = 256 lanes x 8
            int idx = tid * 8;
            int r = idx >> 5, kc = idx & 31;
            GLOAD_LDS16(A + (size_t)(m0 + r) * DM + k0 + kc, &Asm[idx]);
        }
#pragma unroll
        for (int c = 0; c < 2; c++) {   // B: 128x32 = 4096 elems
            int idx = c * 2048 + tid * 8;
            int r = idx >> 5, kc = idx & 31;
            GLOAD_LDS16(W + (size_t)(n0 + r) * DM + k0 + kc, &Bsm[idx]);
        }
        __syncthreads();
        bf16x8 af[2], bfv[4];
#pragma unroll
        for (int i = 0; i < 2; i++)
            af[i] = *(const bf16x8*)(&Asm[(wm + i * 16 + l15) * 32 + quad * 8]);
#pragma unroll
        for (int j = 0; j < 4; j++)
            bfv[j] = *(const bf16x8*)(&Bsm[(wn + j * 16 + l15) * 32 + quad * 8]);
#pragma unroll
        for (int i = 0; i < 2; i++)
#pragma unroll
            for (int j = 0; j < 4; j++)
                acc[i][j] = MFMA16(af[i], bfv[j], acc[i][j]);
        __syncthreads();
    }

#pragma unroll
    for (int i = 0; i < 2; i++)
#pragma unroll
        for (int r = 0; r < 4; r++) {
            int m = m0 + wm + i * 16 + quad * 4 + r;
#pragma unroll
            for (int j = 0; j < 4; j++) {
                int col = n0 + wn + j * 16 + l15;
                __hip_bfloat16 bb = __float2bfloat16(acc[i][j][r]);
                unsigned int u = ((unsigned int)(*(unsigned short*)&bb)) << 16;
                out[(size_t)m * DM + col] = __uint_as_float(u);
            }
        }
}

// ---------------------------------------------------------------------------
extern "C" void kernel_launch(void* const* d_in, const int* in_sizes, int n_in,
                              void* d_out, int out_size, void* d_ws, size_t ws_size,
                              hipStream_t stream)
{
    const float* x  = (const float*)d_in[0];
    const float* wq = (const float*)d_in[1];
    const float* wk = (const float*)d_in[2];
    const float* wv = (const float*)d_in[3];
    const float* wo = (const float*)d_in[4];
    float* out = (float*)d_out;

    const size_t xe = (size_t)2 * S_LEN * DM;
    const size_t we = (size_t)DM * DM;
    __hip_bfloat16* xb  = (__hip_bfloat16*)d_ws;
    __hip_bfloat16* wqb = xb + xe;
    __hip_bfloat16* wkb = wqb + we;
    __hip_bfloat16* wvb = wkb + we;
    __hip_bfloat16* wob = wvb + we;
    __hip_bfloat16* qws = wob + we;
    __hip_bfloat16* kws = qws + xe;
    __hip_bfloat16* vws = kws + xe;   // V^T (B,H,hd,S)
    __hip_bfloat16* aws = vws + xe;
    float2* tab = (float2*)aws;       // RoPE table: reuses attn_out region,
                                      // consumed (K-rope) before aws is written

    dim3 blk(256, 1, 1);
    convert_kernel<<<dim3(1024, 9, 1), blk, 0, stream>>>(x, wq, wk, wv, wo,
                                                         xb, wqb, wkb, wvb, wob, tab);
    qkv_kernel<<<dim3(8, 32, 3), blk, 0, stream>>>(xb, wqb, wkb, wvb, qws, kws, vws);
    rope_kernel<<<dim3(2048, 1, 1), blk, 0, stream>>>(kws, tab);
    attn_kernel<<<dim3(32, 16, 1), blk, 0, stream>>>(qws, kws, vws, aws);
    oproj_kernel<<<dim3(8, 64, 1), blk, 0, stream>>>(aws, wob, out);
}